// Round 6
// baseline (141.309 us; speedup 1.0000x reference)
//
#include <hip/hip_runtime.h>

typedef unsigned short u16;
typedef unsigned int   u32;
typedef __attribute__((ext_vector_type(8))) short bf8;   // 8 bf16 (4 VGPRs)
typedef __attribute__((ext_vector_type(4))) float f4;    // 4 fp32 (C/D frag)

#define DF __device__ __forceinline__

// ---------- helpers ----------
DF float bf2f(u16 h){ u32 u = ((u32)h) << 16; float f; __builtin_memcpy(&f, &u, 4); return f; }
DF u16 f2bf(float f){ u32 u; __builtin_memcpy(&u, &f, 4); u = (u + 0x7FFFu + ((u >> 16) & 1u)) >> 16; return (u16)u; }
DF float fexp2(float x){ return __builtin_amdgcn_exp2f(x); }
DF float frcp (float x){ return __builtin_amdgcn_rcpf(x); }
DF float tanhF(float x){ float e = fexp2(2.8853900817779268f * x); return 1.0f - 2.0f * frcp(e + 1.0f); }
DF float sigF (float x){ return frcp(1.0f + fexp2(-1.4426950408889634f * x)); }
DF float4 ld4u(const float* p){ float4 v; __builtin_memcpy(&v, p, 16); return v; }
// pack 2 fp32 -> 2 bf16 (RTNE): bits[15:0]=bf16(lo), bits[31:16]=bf16(hi)
DF u32 cvtpk(float lo, float hi){ u32 r; asm("v_cvt_pk_bf16_f32 %0, %1, %2" : "=v"(r) : "v"(lo), "v"(hi)); return r; }

// packed fragment-ordered weights: [mat 16][ntile 8][kstep 4][lane 64][8 bf16]
DF const bf8* fragp(const u16* packed, int w, int nt, int ks, int lane){
  return reinterpret_cast<const bf8*>(packed + (((w * 32 + nt * 4 + ks) * 64 + lane) * 8));
}
// pm_w1 extension: 5 k-steps (K padded 135->160 with zeros), groups appended at 512
DF const bf8* fragp_pm1(const u16* packed, int nt, int ks, int lane){
  return reinterpret_cast<const bf8*>(packed + (((512 + nt * 5 + ks) * 64 + lane) * 8));
}

struct WPtrs { const float* p[16]; };

// ---------- K0: pack fp32 weights into MFMA B-fragment order (bf16) ----------
__global__ __launch_bounds__(256) void k_pack(WPtrs wp, u16* __restrict__ packed){
  int bi = blockIdx.x;
  int lane = threadIdx.x & 63, warp = threadIdx.x >> 6;
  if(bi == 16){
    const float* __restrict__ src = wp.p[14];
    u16* __restrict__ dst = packed + 512 * 64 * 8;
    for(int i = warp; i < 40; i += 4){
      int nt = i / 5, ks = i - nt * 5;
      int col = nt * 16 + (lane & 15);
      int kb  = ks * 32 + (lane >> 4) * 8;
      u16* o = dst + (i * 64 + lane) * 8;
      for(int j = 0; j < 8; j++){
        int row = kb + j;
        o[j] = (row < 135) ? f2bf(src[row * 128 + col]) : (u16)0;
      }
    }
    return;
  }
  const float* __restrict__ src = wp.p[bi];
  u16* __restrict__ dst = packed + bi * 32 * 64 * 8;
  for(int i = warp; i < 32; i += 4){
    int nt = i >> 2, ks = i & 3;
    int col = nt * 16 + (lane & 15);
    int kb  = ks * 32 + (lane >> 4) * 8;
    u16* o = dst + (i * 64 + lane) * 8;
    for(int j = 0; j < 8; j++) o[j] = f2bf(src[(kb + j) * 128 + col]);
  }
}

// ---------- K1: node precompute (64 rows/block, warp = nt, weights in regs) ----------
__global__ __launch_bounds__(512) void k_node_pre(
    const float* __restrict__ hidden, const float* __restrict__ inputs,
    const u16* __restrict__ packed,
    const float* __restrict__ res_b1, const float* __restrict__ res_b2,
    float* __restrict__ Ptop, float* __restrict__ Pbot, float* __restrict__ res2)
{
  __shared__ __align__(16) u16 hid[64 * 136];
  __shared__ __align__(16) u16 inp[64 * 136];
  __shared__ __align__(16) u16 t1s[64 * 136];
  int row0 = blockIdx.x * 64;
  int t = threadIdx.x, lane = t & 63, w = t >> 6;
  int lrow = lane & 15, lk = lane >> 4;
  for(int i = t; i < 64 * 128; i += 512){
    int rr = i >> 7, cc = i & 127;
    hid[rr * 136 + cc] = f2bf(hidden[(row0 + rr) * 128 + cc]);
    inp[rr * 136 + cc] = f2bf(inputs[(row0 + rr) * 128 + cc]);
  }
  bf8 f0[4], f1[4], f5[4], f6[4];
  #pragma unroll
  for(int k = 0; k < 4; k++){
    f0[k] = *fragp(packed, 0, w, k, lane);
    f1[k] = *fragp(packed, 1, w, k, lane);
    f5[k] = *fragp(packed, 5, w, k, lane);
    f6[k] = *fragp(packed, 6, w, k, lane);
  }
  int col = w * 16 + lrow;
  float rb1 = res_b1[col], rb2 = res_b2[col];
  __syncthreads();
  #pragma unroll
  for(int m = 0; m < 4; m++){
    bf8 a[4], a2[4];
    #pragma unroll
    for(int k = 0; k < 4; k++){
      a[k]  = *reinterpret_cast<const bf8*>(&hid[(m * 16 + lrow) * 136 + k * 32 + lk * 8]);
      a2[k] = *reinterpret_cast<const bf8*>(&inp[(m * 16 + lrow) * 136 + k * 32 + lk * 8]);
    }
    f4 c0 = {0.f,0.f,0.f,0.f}, c1 = {0.f,0.f,0.f,0.f}, c2 = {0.f,0.f,0.f,0.f};
    #pragma unroll
    for(int k = 0; k < 4; k++){
      c0 = __builtin_amdgcn_mfma_f32_16x16x32_bf16(a[k],  f0[k], c0, 0, 0, 0);
      c1 = __builtin_amdgcn_mfma_f32_16x16x32_bf16(a[k],  f1[k], c1, 0, 0, 0);
      c2 = __builtin_amdgcn_mfma_f32_16x16x32_bf16(a2[k], f5[k], c2, 0, 0, 0);
    }
    #pragma unroll
    for(int q = 0; q < 4; q++){
      int gr = row0 + m * 16 + lk * 4 + q;
      Ptop[gr * 128 + col] = c0[q];
      Pbot[gr * 128 + col] = c1[q];
      float v = c2[q] + rb1; v = v > 0.f ? v : 0.f;
      t1s[(m * 16 + lk * 4 + q) * 136 + col] = f2bf(v);
    }
  }
  __syncthreads();
  #pragma unroll
  for(int m = 0; m < 4; m++){
    bf8 a3[4];
    #pragma unroll
    for(int k = 0; k < 4; k++)
      a3[k] = *reinterpret_cast<const bf8*>(&t1s[(m * 16 + lrow) * 136 + k * 32 + lk * 8]);
    f4 c = {0.f,0.f,0.f,0.f};
    #pragma unroll
    for(int k = 0; k < 4; k++)
      c = __builtin_amdgcn_mfma_f32_16x16x32_bf16(a3[k], f6[k], c, 0, 0, 0);
    #pragma unroll
    for(int q = 0; q < 4; q++){
      float v = c[q] + rb2; v = v > 0.f ? v : 0.f;
      res2[(row0 + m * 16 + lk * 4 + q) * 128 + col] = v;
    }
  }
}

// ---------- K2: merged edge kernel (pm then msg per (b,r) block), 4 warps, 2 nt/warp ----------
// bufA [112][128] bf16, 256B rows = 16 slots of 16B, swizzled slot ^= (row&7).
// tail [112][8] bf16 (pm K-tail cols 128..134 + pad), linear.
__global__ __launch_bounds__(256, 5) void k_edge(
    const float* __restrict__ EA,
    const float* __restrict__ Ptop, const float* __restrict__ Pbot,
    const float* __restrict__ msg_b1, const float* __restrict__ msg_b2,
    const float* __restrict__ pm_b1, const float* __restrict__ pm_b2,
    const u16* __restrict__ packed,
    float* __restrict__ hnode, float* __restrict__ pnode)
{
  __shared__ __align__(16) u16 bufA[112 * 128];
  __shared__ __align__(16) u16 tail[112 * 8];
  char* bb = (char*)bufA;
  char* tb = (char*)tail;
  int blk = blockIdx.x;
  int b = blk / 100, r = blk - b * 100;
  int t = threadIdx.x, lane = t & 63, w = t >> 6;
  int lrow = lane & 15, lk = lane >> 4;
  int n0 = 2 * w, n1 = 2 * w + 1;

  // ================= pm phase =================
  {
    bf8 w1a[5], w1b[5];
    #pragma unroll
    for(int k = 0; k < 5; k++){ w1a[k] = *fragp_pm1(packed, n0, k, lane); w1b[k] = *fragp_pm1(packed, n1, k, lane); }
    float b1a = pm_b1[n0 * 16 + lrow], b1b = pm_b1[n1 * 16 + lrow];
    // stage main cols 0..127 (99 rows, 16 x 16B groups per row, swizzled)
    for(int i = t; i < 99 * 16; i += 256){
      int row = i >> 4, g = i & 15;
      int s = row + (row >= r ? 1 : 0);
      int e = s * 99 + (r < s ? r : r - 1);
      const float* rp = EA + ((size_t)(b * 9900 + e)) * 135 + g * 8;
      float4 v0 = ld4u(rp), v1 = ld4u(rp + 4);
      u32 pk[4] = {cvtpk(v0.x, v0.y), cvtpk(v0.z, v0.w), cvtpk(v1.x, v1.y), cvtpk(v1.z, v1.w)};
      *reinterpret_cast<uint4*>(bb + row * 256 + ((g ^ (row & 7)) << 4)) = *reinterpret_cast<const uint4*>(pk);
    }
    // stage tail cols 128..134 (+pad)
    for(int row = t; row < 99; row += 256){
      int s = row + (row >= r ? 1 : 0);
      int e = s * 99 + (r < s ? r : r - 1);
      const float* rp = EA + ((size_t)(b * 9900 + e)) * 135 + 128;
      float4 v0 = ld4u(rp);
      u32 pk[4] = {cvtpk(v0.x, v0.y), cvtpk(v0.z, v0.w), cvtpk(rp[4], rp[5]), cvtpk(rp[6], 0.f)};
      *reinterpret_cast<uint4*>(tb + row * 16) = *reinterpret_cast<const uint4*>(pk);
    }
    __syncthreads();
    // layer 1 in-place (per-m barrier; writes hit only rows already read by all warps)
    #pragma unroll
    for(int m = 0; m < 7; m++){
      int arow = m * 16 + lrow;
      int sw = (arow & 7);
      bf8 a[5];
      #pragma unroll
      for(int k = 0; k < 4; k++)
        a[k] = *reinterpret_cast<const bf8*>(bb + arow * 256 + (((k * 4 + lk) ^ sw) << 4));
      bf8 a4 = {0,0,0,0,0,0,0,0};
      if(lk == 0) a4 = *reinterpret_cast<const bf8*>(tb + arow * 16);
      f4 c0 = {0.f,0.f,0.f,0.f}, c1 = {0.f,0.f,0.f,0.f};
      #pragma unroll
      for(int k = 0; k < 4; k++){
        c0 = __builtin_amdgcn_mfma_f32_16x16x32_bf16(a[k], w1a[k], c0, 0, 0, 0);
        c1 = __builtin_amdgcn_mfma_f32_16x16x32_bf16(a[k], w1b[k], c1, 0, 0, 0);
      }
      c0 = __builtin_amdgcn_mfma_f32_16x16x32_bf16(a4, w1a[4], c0, 0, 0, 0);
      c1 = __builtin_amdgcn_mfma_f32_16x16x32_bf16(a4, w1b[4], c1, 0, 0, 0);
      __syncthreads();   // all warps finished reading ea tile m
      #pragma unroll
      for(int qp = 0; qp < 2; qp++){
        float v0 = c0[2*qp]   + b1a; v0 = v0 > 0.f ? v0 : 0.f;
        float u0 = c0[2*qp+1] + b1a; u0 = u0 > 0.f ? u0 : 0.f;
        float v1 = c1[2*qp]   + b1b; v1 = v1 > 0.f ? v1 : 0.f;
        float u1 = c1[2*qp+1] + b1b; u1 = u1 > 0.f ? u1 : 0.f;
        u32 p0 = cvtpk(v0, u0), p1 = cvtpk(v1, u1);
        int row0_ = m * 16 + lk * 4 + 2 * qp;
        int sw0 = (row0_ & 7) << 4, sw1 = ((row0_ + 1) & 7) << 4;
        *reinterpret_cast<u16*>(bb + row0_ * 256       + (((n0 * 16 + lrow) * 2) ^ sw0)) = (u16)p0;
        *reinterpret_cast<u16*>(bb + (row0_ + 1) * 256 + (((n0 * 16 + lrow) * 2) ^ sw1)) = (u16)(p0 >> 16);
        *reinterpret_cast<u16*>(bb + row0_ * 256       + (((n1 * 16 + lrow) * 2) ^ sw0)) = (u16)p1;
        *reinterpret_cast<u16*>(bb + (row0_ + 1) * 256 + (((n1 * 16 + lrow) * 2) ^ sw1)) = (u16)(p1 >> 16);
      }
    }
    __syncthreads();
    // layer 2 + column-sum
    bf8 w2a[4], w2b[4];
    #pragma unroll
    for(int k = 0; k < 4; k++){ w2a[k] = *fragp(packed, 15, n0, k, lane); w2b[k] = *fragp(packed, 15, n1, k, lane); }
    float b2a = pm_b2[n0 * 16 + lrow], b2b = pm_b2[n1 * 16 + lrow];
    float acc0 = 0.f, acc1 = 0.f;
    #pragma unroll
    for(int m = 0; m < 7; m++){
      int arow = m * 16 + lrow;
      int sw = (arow & 7);
      bf8 a[4];
      #pragma unroll
      for(int k = 0; k < 4; k++)
        a[k] = *reinterpret_cast<const bf8*>(bb + arow * 256 + (((k * 4 + lk) ^ sw) << 4));
      f4 c0 = {0.f,0.f,0.f,0.f}, c1 = {0.f,0.f,0.f,0.f};
      #pragma unroll
      for(int k = 0; k < 4; k++){
        c0 = __builtin_amdgcn_mfma_f32_16x16x32_bf16(a[k], w2a[k], c0, 0, 0, 0);
        c1 = __builtin_amdgcn_mfma_f32_16x16x32_bf16(a[k], w2b[k], c1, 0, 0, 0);
      }
      #pragma unroll
      for(int q = 0; q < 4; q++){
        int rr = m * 16 + lk * 4 + q;
        if(rr < 99){
          float v0 = c0[q] + b2a; acc0 += (v0 > 0.f ? v0 : 0.f);
          float v1 = c1[q] + b2b; acc1 += (v1 > 0.f ? v1 : 0.f);
        }
      }
    }
    acc0 += __shfl_xor(acc0, 16); acc0 += __shfl_xor(acc0, 32);
    acc1 += __shfl_xor(acc1, 16); acc1 += __shfl_xor(acc1, 32);
    if(lane < 16){
      float* dst = pnode + ((size_t)b * 100 + r) * 128;
      dst[n0 * 16 + lane] = acc0 * (1.0f / 99.0f);
      dst[n1 * 16 + lane] = acc1 * (1.0f / 99.0f);
    }
  }
  __syncthreads();   // all warps done reading pm h1 before msg overwrites bufA

  // ================= msg phase =================
  {
    bf8 w2a[4], w2b[4];
    #pragma unroll
    for(int k = 0; k < 4; k++){ w2a[k] = *fragp(packed, 13, n0, k, lane); w2b[k] = *fragp(packed, 13, n1, k, lane); }
    float b2a = msg_b2[n0 * 16 + lrow], b2b = msg_b2[n1 * 16 + lrow];
    int c4 = t & 31;
    float4 pt = *reinterpret_cast<const float4*>(Ptop + ((size_t)b * 100 + r) * 128 + c4 * 4);
    float4 mb = *reinterpret_cast<const float4*>(msg_b1 + c4 * 4);
    pt.x += mb.x; pt.y += mb.y; pt.z += mb.z; pt.w += mb.w;
    // h1 = tanh(pt + Pbot[s]) -> bufA (swizzled 8B writes)
    for(int row = t >> 5; row < 99; row += 8){
      int s = row + (row >= r ? 1 : 0);
      float4 v = *reinterpret_cast<const float4*>(Pbot + ((size_t)b * 100 + s) * 128 + c4 * 4);
      u32 pk[2] = {cvtpk(tanhF(pt.x + v.x), tanhF(pt.y + v.y)),
                   cvtpk(tanhF(pt.z + v.z), tanhF(pt.w + v.w))};
      *reinterpret_cast<uint2*>(bb + row * 256 + ((8 * c4) ^ ((row & 7) << 4))) = *reinterpret_cast<const uint2*>(pk);
    }
    __syncthreads();
    float acc0 = 0.f, acc1 = 0.f;
    #pragma unroll
    for(int m = 0; m < 7; m++){
      int arow = m * 16 + lrow;
      int sw = (arow & 7);
      bf8 a[4];
      #pragma unroll
      for(int k = 0; k < 4; k++)
        a[k] = *reinterpret_cast<const bf8*>(bb + arow * 256 + (((k * 4 + lk) ^ sw) << 4));
      f4 c0 = {0.f,0.f,0.f,0.f}, c1 = {0.f,0.f,0.f,0.f};
      #pragma unroll
      for(int k = 0; k < 4; k++){
        c0 = __builtin_amdgcn_mfma_f32_16x16x32_bf16(a[k], w2a[k], c0, 0, 0, 0);
        c1 = __builtin_amdgcn_mfma_f32_16x16x32_bf16(a[k], w2b[k], c1, 0, 0, 0);
      }
      #pragma unroll
      for(int q = 0; q < 4; q++){
        int rr = m * 16 + lk * 4 + q;
        if(rr < 99){
          acc0 += tanhF(c0[q] + b2a);
          acc1 += tanhF(c1[q] + b2b);
        }
      }
    }
    acc0 += __shfl_xor(acc0, 16); acc0 += __shfl_xor(acc0, 32);
    acc1 += __shfl_xor(acc1, 16); acc1 += __shfl_xor(acc1, 32);
    if(lane < 16){
      float* dst = hnode + ((size_t)b * 100 + r) * 128;
      dst[n0 * 16 + lane] = acc0 * (1.0f / 99.0f);
      dst[n1 * 16 + lane] = acc1 * (1.0f / 99.0f);
    }
  }
}

// ---------- K3: GRU gates + out MLP (64 rows/block, warp = nt, weights in regs) ----------
__global__ __launch_bounds__(512) void k_final(
    const float* __restrict__ hnode, const float* __restrict__ pnode,
    const float* __restrict__ res2, const float* __restrict__ hidden,
    const u16* __restrict__ packed,
    const float* __restrict__ ir_b, const float* __restrict__ ii_b, const float* __restrict__ in_b,
    const float* __restrict__ ob1, const float* __restrict__ ob2, const float* __restrict__ ob3,
    float* __restrict__ out_pred, float* __restrict__ out_hid)
{
  __shared__ __align__(16) u16 hn[64 * 136];
  __shared__ __align__(16) u16 pr[64 * 136];
  __shared__ __align__(16) u16 hw[64 * 136];
  int row0 = blockIdx.x * 64;
  int t = threadIdx.x, lane = t & 63, w = t >> 6;
  int lrow = lane & 15, lk = lane >> 4;
  for(int i = t; i < 64 * 128; i += 512){
    int rr = i >> 7, cc = i & 127;
    hn[rr * 136 + cc] = f2bf(hnode[(row0 + rr) * 128 + cc]);
    pr[rr * 136 + cc] = f2bf(pnode[(row0 + rr) * 128 + cc] + res2[(row0 + rr) * 128 + cc]);
  }
  int col = w * 16 + lrow;
  bf8 mhr[4], mhi[4], mhh[4], mir[4], mii[4], min_[4];
  #pragma unroll
  for(int k = 0; k < 4; k++){
    mhr[k]  = *fragp(packed, 2, w, k, lane);
    mhi[k]  = *fragp(packed, 3, w, k, lane);
    mhh[k]  = *fragp(packed, 4, w, k, lane);
    mir[k]  = *fragp(packed, 7, w, k, lane);
    mii[k]  = *fragp(packed, 8, w, k, lane);
    min_[k] = *fragp(packed, 9, w, k, lane);
  }
  float bir = ir_b[col], bii = ii_b[col], bin = in_b[col];
  __syncthreads();
  #pragma unroll
  for(int m = 0; m < 4; m++){
    bf8 a[4], p[4];
    #pragma unroll
    for(int k = 0; k < 4; k++){
      a[k] = *reinterpret_cast<const bf8*>(&hn[(m * 16 + lrow) * 136 + k * 32 + lk * 8]);
      p[k] = *reinterpret_cast<const bf8*>(&pr[(m * 16 + lrow) * 136 + k * 32 + lk * 8]);
    }
    f4 cR = {0.f,0.f,0.f,0.f}, cI = {0.f,0.f,0.f,0.f}, cN = {0.f,0.f,0.f,0.f};
    f4 dR = {0.f,0.f,0.f,0.f}, dI = {0.f,0.f,0.f,0.f}, dN = {0.f,0.f,0.f,0.f};
    #pragma unroll
    for(int k = 0; k < 4; k++){
      cR = __builtin_amdgcn_mfma_f32_16x16x32_bf16(a[k], mhr[k],  cR, 0, 0, 0);
      cI = __builtin_amdgcn_mfma_f32_16x16x32_bf16(a[k], mhi[k],  cI, 0, 0, 0);
      cN = __builtin_amdgcn_mfma_f32_16x16x32_bf16(a[k], mhh[k],  cN, 0, 0, 0);
      dR = __builtin_amdgcn_mfma_f32_16x16x32_bf16(p[k], mir[k],  dR, 0, 0, 0);
      dI = __builtin_amdgcn_mfma_f32_16x16x32_bf16(p[k], mii[k],  dI, 0, 0, 0);
      dN = __builtin_amdgcn_mfma_f32_16x16x32_bf16(p[k], min_[k], dN, 0, 0, 0);
    }
    #pragma unroll
    for(int q = 0; q < 4; q++){
      int gr = row0 + m * 16 + lk * 4 + q;
      float rv = sigF(dR[q] + bir + cR[q]);
      float iv = sigF(dI[q] + bii + cI[q]);
      float nv = tanhF(dN[q] + bin + rv * cN[q]);
      float hold = hidden[gr * 128 + col];
      float hnew = (1.f - iv) * nv + iv * hold;
      out_hid[gr * 128 + col] = hnew;
      hw[(m * 16 + lk * 4 + q) * 136 + col] = f2bf(hnew);
    }
  }
  __syncthreads();
  {
    bf8 m10[4];
    #pragma unroll
    for(int k = 0; k < 4; k++) m10[k] = *fragp(packed, 10, w, k, lane);
    float bb = ob1[col];
    #pragma unroll
    for(int m = 0; m < 4; m++){
      f4 c = {0.f,0.f,0.f,0.f};
      #pragma unroll
      for(int k = 0; k < 4; k++){
        bf8 a = *reinterpret_cast<const bf8*>(&hw[(m * 16 + lrow) * 136 + k * 32 + lk * 8]);
        c = __builtin_amdgcn_mfma_f32_16x16x32_bf16(a, m10[k], c, 0, 0, 0);
      }
      #pragma unroll
      for(int q = 0; q < 4; q++){
        float v = c[q] + bb; v = v > 0.f ? v : 0.f;
        hn[(m * 16 + lk * 4 + q) * 136 + col] = f2bf(v);
      }
    }
  }
  __syncthreads();
  {
    bf8 m11[4];
    #pragma unroll
    for(int k = 0; k < 4; k++) m11[k] = *fragp(packed, 11, w, k, lane);
    float bb = ob2[col];
    #pragma unroll
    for(int m = 0; m < 4; m++){
      f4 c = {0.f,0.f,0.f,0.f};
      #pragma unroll
      for(int k = 0; k < 4; k++){
        bf8 a = *reinterpret_cast<const bf8*>(&hn[(m * 16 + lrow) * 136 + k * 32 + lk * 8]);
        c = __builtin_amdgcn_mfma_f32_16x16x32_bf16(a, m11[k], c, 0, 0, 0);
      }
      #pragma unroll
      for(int q = 0; q < 4; q++){
        float v = c[q] + bb; v = v > 0.f ? v : 0.f;
        pr[(m * 16 + lk * 4 + q) * 136 + col] = f2bf(v);
      }
    }
  }
  __syncthreads();
  {
    bf8 m12[4];
    #pragma unroll
    for(int k = 0; k < 4; k++) m12[k] = *fragp(packed, 12, w, k, lane);
    float bb = ob3[col];
    #pragma unroll
    for(int m = 0; m < 4; m++){
      f4 c = {0.f,0.f,0.f,0.f};
      #pragma unroll
      for(int k = 0; k < 4; k++){
        bf8 a = *reinterpret_cast<const bf8*>(&pr[(m * 16 + lrow) * 136 + k * 32 + lk * 8]);
        c = __builtin_amdgcn_mfma_f32_16x16x32_bf16(a, m12[k], c, 0, 0, 0);
      }
      #pragma unroll
      for(int q = 0; q < 4; q++)
        out_pred[(row0 + m * 16 + lk * 4 + q) * 128 + col] = c[q] + bb;
    }
  }
}

// ---------- host ----------
extern "C" void kernel_launch(void* const* d_in, const int* in_sizes, int n_in,
                              void* d_out, int out_size, void* d_ws, size_t ws_size,
                              hipStream_t stream)
{
  const float* inputs = (const float*)d_in[0];
  const float* edge   = (const float*)d_in[1];
  const float* hidden = (const float*)d_in[2];
  const float* msg_w1 = (const float*)d_in[3];
  const float* msg_b1 = (const float*)d_in[4];
  const float* msg_w2 = (const float*)d_in[5];
  const float* msg_b2 = (const float*)d_in[6];
  const float* pm_w1  = (const float*)d_in[7];
  const float* pm_b1  = (const float*)d_in[8];
  const float* pm_w2  = (const float*)d_in[9];
  const float* pm_b2  = (const float*)d_in[10];
  const float* res_w1 = (const float*)d_in[11];
  const float* res_b1 = (const float*)d_in[12];
  const float* res_w2 = (const float*)d_in[13];
  const float* res_b2 = (const float*)d_in[14];
  const float* ir_w = (const float*)d_in[15]; const float* ir_b = (const float*)d_in[16];
  const float* ii_w = (const float*)d_in[17]; const float* ii_b = (const float*)d_in[18];
  const float* in_w = (const float*)d_in[19]; const float* in_b = (const float*)d_in[20];
  const float* hr_w = (const float*)d_in[21];
  const float* hi_w = (const float*)d_in[22];
  const float* hh_w = (const float*)d_in[23];
  const float* out_w1 = (const float*)d_in[24]; const float* out_b1 = (const float*)d_in[25];
  const float* out_w2 = (const float*)d_in[26]; const float* out_b2 = (const float*)d_in[27];
  const float* out_w3 = (const float*)d_in[28]; const float* out_b3 = (const float*)d_in[29];

  char* ws = (char*)d_ws;
  u16*   packed = (u16*)ws;                                     // 565248 B used (1 MB reserved)
  float* Ptop   = (float*)(ws + (1 << 20));                     // 1638400 B each
  float* Pbot   = (float*)(ws + (1 << 20) + 1 * 1638400);
  float* res2   = (float*)(ws + (1 << 20) + 2 * 1638400);
  float* hnode  = (float*)(ws + (1 << 20) + 3 * 1638400);
  float* pnode  = (float*)(ws + (1 << 20) + 4 * 1638400);

  WPtrs wp;
  wp.p[0]  = msg_w1;             // msg_w1 top (recv half)
  wp.p[1]  = msg_w1 + 128 * 128; // msg_w1 bottom (send half)
  wp.p[2]  = hr_w;  wp.p[3]  = hi_w;  wp.p[4]  = hh_w;
  wp.p[5]  = res_w1; wp.p[6] = res_w2;
  wp.p[7]  = ir_w;  wp.p[8]  = ii_w;  wp.p[9]  = in_w;
  wp.p[10] = out_w1; wp.p[11] = out_w2; wp.p[12] = out_w3;
  wp.p[13] = msg_w2; wp.p[14] = pm_w1; wp.p[15] = pm_w2;

  k_pack<<<17, 256, 0, stream>>>(wp, packed);
  k_node_pre<<<50, 512, 0, stream>>>(hidden, inputs, packed, res_b1, res_b2, Ptop, Pbot, res2);
  k_edge<<<3200, 256, 0, stream>>>(edge, Ptop, Pbot, msg_b1, msg_b2, pm_b1, pm_b2,
                                   packed, hnode, pnode);
  float* outp = (float*)d_out;
  k_final<<<50, 512, 0, stream>>>(hnode, pnode, res2, hidden, packed,
                                  ir_b, ii_b, in_b, out_b1, out_b2, out_b3,
                                  outp, outp + 32 * 100 * 128);
}

// Round 7
// 118.732 us; speedup vs baseline: 1.1901x; 1.1901x over previous
//
#include <hip/hip_runtime.h>

typedef unsigned short u16;
typedef unsigned int   u32;
typedef __attribute__((ext_vector_type(8))) short bf8;   // 8 bf16 (4 VGPRs)
typedef __attribute__((ext_vector_type(4))) float f4;    // 4 fp32 (C/D frag)

#define DF __device__ __forceinline__

// ---------- helpers ----------
DF float bf2f(u16 h){ u32 u = ((u32)h) << 16; float f; __builtin_memcpy(&f, &u, 4); return f; }
DF u16 f2bf(float f){ u32 u; __builtin_memcpy(&u, &f, 4); u = (u + 0x7FFFu + ((u >> 16) & 1u)) >> 16; return (u16)u; }
DF float fexp2(float x){ return __builtin_amdgcn_exp2f(x); }
DF float frcp (float x){ return __builtin_amdgcn_rcpf(x); }
DF float tanhF(float x){ float e = fexp2(2.8853900817779268f * x); return 1.0f - 2.0f * frcp(e + 1.0f); }
DF float sigF (float x){ return frcp(1.0f + fexp2(-1.4426950408889634f * x)); }
DF float4 ld4u(const float* p){ float4 v; __builtin_memcpy(&v, p, 16); return v; }
// pack 2 fp32 -> 2 bf16 (RTNE): bits[15:0]=bf16(lo), bits[31:16]=bf16(hi)
DF u32 cvtpk(float lo, float hi){ u32 r; asm("v_cvt_pk_bf16_f32 %0, %1, %2" : "=v"(r) : "v"(lo), "v"(hi)); return r; }

// packed fragment-ordered weights: [mat 16][ntile 8][kstep 4][lane 64][8 bf16]
DF const bf8* fragp(const u16* packed, int w, int nt, int ks, int lane){
  return reinterpret_cast<const bf8*>(packed + (((w * 32 + nt * 4 + ks) * 64 + lane) * 8));
}
// pm_w1 extension: 5 k-steps (K padded 135->160 with zeros), groups appended at 512
DF const bf8* fragp_pm1(const u16* packed, int nt, int ks, int lane){
  return reinterpret_cast<const bf8*>(packed + (((512 + nt * 5 + ks) * 64 + lane) * 8));
}

struct WPtrs { const float* p[16]; };

// ---------- K0: pack fp32 weights into MFMA B-fragment order (bf16) ----------
__global__ __launch_bounds__(256) void k_pack(WPtrs wp, u16* __restrict__ packed){
  int bi = blockIdx.x;
  int lane = threadIdx.x & 63, warp = threadIdx.x >> 6;
  if(bi == 16){
    const float* __restrict__ src = wp.p[14];
    u16* __restrict__ dst = packed + 512 * 64 * 8;
    for(int i = warp; i < 40; i += 4){
      int nt = i / 5, ks = i - nt * 5;
      int col = nt * 16 + (lane & 15);
      int kb  = ks * 32 + (lane >> 4) * 8;
      u16* o = dst + (i * 64 + lane) * 8;
      for(int j = 0; j < 8; j++){
        int row = kb + j;
        o[j] = (row < 135) ? f2bf(src[row * 128 + col]) : (u16)0;
      }
    }
    return;
  }
  const float* __restrict__ src = wp.p[bi];
  u16* __restrict__ dst = packed + bi * 32 * 64 * 8;
  for(int i = warp; i < 32; i += 4){
    int nt = i >> 2, ks = i & 3;
    int col = nt * 16 + (lane & 15);
    int kb  = ks * 32 + (lane >> 4) * 8;
    u16* o = dst + (i * 64 + lane) * 8;
    for(int j = 0; j < 8; j++) o[j] = f2bf(src[(kb + j) * 128 + col]);
  }
}

// ---------- K1: node precompute (64 rows/block, warp = nt, weights in regs) ----------
__global__ __launch_bounds__(512) void k_node_pre(
    const float* __restrict__ hidden, const float* __restrict__ inputs,
    const u16* __restrict__ packed,
    const float* __restrict__ res_b1, const float* __restrict__ res_b2,
    float* __restrict__ Ptop, float* __restrict__ Pbot, float* __restrict__ res2)
{
  __shared__ __align__(16) u16 hid[64 * 136];
  __shared__ __align__(16) u16 inp[64 * 136];
  __shared__ __align__(16) u16 t1s[64 * 136];
  int row0 = blockIdx.x * 64;
  int t = threadIdx.x, lane = t & 63, w = t >> 6;
  int lrow = lane & 15, lk = lane >> 4;
  for(int i = t; i < 64 * 128; i += 512){
    int rr = i >> 7, cc = i & 127;
    hid[rr * 136 + cc] = f2bf(hidden[(row0 + rr) * 128 + cc]);
    inp[rr * 136 + cc] = f2bf(inputs[(row0 + rr) * 128 + cc]);
  }
  bf8 f0[4], f1[4], f5[4], f6[4];
  #pragma unroll
  for(int k = 0; k < 4; k++){
    f0[k] = *fragp(packed, 0, w, k, lane);
    f1[k] = *fragp(packed, 1, w, k, lane);
    f5[k] = *fragp(packed, 5, w, k, lane);
    f6[k] = *fragp(packed, 6, w, k, lane);
  }
  int col = w * 16 + lrow;
  float rb1 = res_b1[col], rb2 = res_b2[col];
  __syncthreads();
  #pragma unroll
  for(int m = 0; m < 4; m++){
    bf8 a[4], a2[4];
    #pragma unroll
    for(int k = 0; k < 4; k++){
      a[k]  = *reinterpret_cast<const bf8*>(&hid[(m * 16 + lrow) * 136 + k * 32 + lk * 8]);
      a2[k] = *reinterpret_cast<const bf8*>(&inp[(m * 16 + lrow) * 136 + k * 32 + lk * 8]);
    }
    f4 c0 = {0.f,0.f,0.f,0.f}, c1 = {0.f,0.f,0.f,0.f}, c2 = {0.f,0.f,0.f,0.f};
    #pragma unroll
    for(int k = 0; k < 4; k++){
      c0 = __builtin_amdgcn_mfma_f32_16x16x32_bf16(a[k],  f0[k], c0, 0, 0, 0);
      c1 = __builtin_amdgcn_mfma_f32_16x16x32_bf16(a[k],  f1[k], c1, 0, 0, 0);
      c2 = __builtin_amdgcn_mfma_f32_16x16x32_bf16(a2[k], f5[k], c2, 0, 0, 0);
    }
    #pragma unroll
    for(int q = 0; q < 4; q++){
      int gr = row0 + m * 16 + lk * 4 + q;
      Ptop[gr * 128 + col] = c0[q];
      Pbot[gr * 128 + col] = c1[q];
      float v = c2[q] + rb1; v = v > 0.f ? v : 0.f;
      t1s[(m * 16 + lk * 4 + q) * 136 + col] = f2bf(v);
    }
  }
  __syncthreads();
  #pragma unroll
  for(int m = 0; m < 4; m++){
    bf8 a3[4];
    #pragma unroll
    for(int k = 0; k < 4; k++)
      a3[k] = *reinterpret_cast<const bf8*>(&t1s[(m * 16 + lrow) * 136 + k * 32 + lk * 8]);
    f4 c = {0.f,0.f,0.f,0.f};
    #pragma unroll
    for(int k = 0; k < 4; k++)
      c = __builtin_amdgcn_mfma_f32_16x16x32_bf16(a3[k], f6[k], c, 0, 0, 0);
    #pragma unroll
    for(int q = 0; q < 4; q++){
      float v = c[q] + rb2; v = v > 0.f ? v : 0.f;
      res2[(row0 + m * 16 + lk * 4 + q) * 128 + col] = v;
    }
  }
}

// ---------- K2: merged edge kernel (pm then msg per (b,r) block), 4 warps, 2 nt/warp ----------
// bufA [112][128] bf16, 256B rows = 16 slots of 16B, swizzled slot ^= (row&7).
// tail [112][8] bf16 (pm K-tail cols 128..134 + pad), linear.
// Layer-1 runs in two row-chunks fully in registers (no per-m barriers):
//   A: read rows 0..63 -> 8 accs | BAR | write h1 rows 0..63
//   B: read rows 64..111 -> 6 accs | BAR | write h1 rows 64..111 | BAR | layer 2
__global__ __launch_bounds__(256, 4) void k_edge(
    const float* __restrict__ EA,
    const float* __restrict__ Ptop, const float* __restrict__ Pbot,
    const float* __restrict__ msg_b1, const float* __restrict__ msg_b2,
    const float* __restrict__ pm_b1, const float* __restrict__ pm_b2,
    const u16* __restrict__ packed,
    float* __restrict__ hnode, float* __restrict__ pnode)
{
  __shared__ __align__(16) u16 bufA[112 * 128];
  __shared__ __align__(16) u16 tail[112 * 8];
  char* bb = (char*)bufA;
  char* tb = (char*)tail;
  int blk = blockIdx.x;
  int b = blk / 100, r = blk - b * 100;
  int t = threadIdx.x, lane = t & 63, w = t >> 6;
  int lrow = lane & 15, lk = lane >> 4;
  int n0 = 2 * w, n1 = 2 * w + 1;

  // ================= pm phase =================
  {
    // stage main cols 0..127 (99 rows, 16 x 16B groups per row, swizzled)
    for(int i = t; i < 99 * 16; i += 256){
      int row = i >> 4, g = i & 15;
      int s = row + (row >= r ? 1 : 0);
      int e = s * 99 + (r < s ? r : r - 1);
      const float* rp = EA + ((size_t)(b * 9900 + e)) * 135 + g * 8;
      float4 v0 = ld4u(rp), v1 = ld4u(rp + 4);
      u32 pk[4] = {cvtpk(v0.x, v0.y), cvtpk(v0.z, v0.w), cvtpk(v1.x, v1.y), cvtpk(v1.z, v1.w)};
      *reinterpret_cast<uint4*>(bb + row * 256 + ((g ^ (row & 7)) << 4)) = *reinterpret_cast<const uint4*>(pk);
    }
    // stage tail cols 128..134 (+pad)
    for(int row = t; row < 99; row += 256){
      int s = row + (row >= r ? 1 : 0);
      int e = s * 99 + (r < s ? r : r - 1);
      const float* rp = EA + ((size_t)(b * 9900 + e)) * 135 + 128;
      float4 v0 = ld4u(rp);
      u32 pk[4] = {cvtpk(v0.x, v0.y), cvtpk(v0.z, v0.w), cvtpk(rp[4], rp[5]), cvtpk(rp[6], 0.f)};
      *reinterpret_cast<uint4*>(tb + row * 16) = *reinterpret_cast<const uint4*>(pk);
    }
    bf8 w1a[5], w1b[5];
    #pragma unroll
    for(int k = 0; k < 5; k++){ w1a[k] = *fragp_pm1(packed, n0, k, lane); w1b[k] = *fragp_pm1(packed, n1, k, lane); }
    float b1a = pm_b1[n0 * 16 + lrow], b1b = pm_b1[n1 * 16 + lrow];
    __syncthreads();   // BAR1: ea staged

    // ---- layer 1 phase A: m = 0..3 (reads rows 0..63), accumulate in regs
    f4 cA0[4], cA1[4];
    #pragma unroll
    for(int m = 0; m < 4; m++){
      int arow = m * 16 + lrow, sw = arow & 7;
      bf8 a[4];
      #pragma unroll
      for(int k = 0; k < 4; k++)
        a[k] = *reinterpret_cast<const bf8*>(bb + arow * 256 + (((k * 4 + lk) ^ sw) << 4));
      bf8 a4 = {0,0,0,0,0,0,0,0};
      if(lk == 0) a4 = *reinterpret_cast<const bf8*>(tb + arow * 16);
      f4 c0 = {0.f,0.f,0.f,0.f}, c1 = {0.f,0.f,0.f,0.f};
      #pragma unroll
      for(int k = 0; k < 4; k++){
        c0 = __builtin_amdgcn_mfma_f32_16x16x32_bf16(a[k], w1a[k], c0, 0, 0, 0);
        c1 = __builtin_amdgcn_mfma_f32_16x16x32_bf16(a[k], w1b[k], c1, 0, 0, 0);
      }
      c0 = __builtin_amdgcn_mfma_f32_16x16x32_bf16(a4, w1a[4], c0, 0, 0, 0);
      c1 = __builtin_amdgcn_mfma_f32_16x16x32_bf16(a4, w1b[4], c1, 0, 0, 0);
      cA0[m] = c0; cA1[m] = c1;
    }
    __syncthreads();   // BAR2: all warps done reading rows 0..63

    // write h1 rows 0..63 (overwrites ea rows 0..63; disjoint from phase-B reads)
    #pragma unroll
    for(int m = 0; m < 4; m++){
      #pragma unroll
      for(int qp = 0; qp < 2; qp++){
        float v0 = cA0[m][2*qp]   + b1a; v0 = v0 > 0.f ? v0 : 0.f;
        float u0 = cA0[m][2*qp+1] + b1a; u0 = u0 > 0.f ? u0 : 0.f;
        float v1 = cA1[m][2*qp]   + b1b; v1 = v1 > 0.f ? v1 : 0.f;
        float u1 = cA1[m][2*qp+1] + b1b; u1 = u1 > 0.f ? u1 : 0.f;
        u32 p0 = cvtpk(v0, u0), p1 = cvtpk(v1, u1);
        int row0_ = m * 16 + lk * 4 + 2 * qp;
        int sw0 = (row0_ & 7) << 4, sw1 = ((row0_ + 1) & 7) << 4;
        *reinterpret_cast<u16*>(bb + row0_ * 256       + (((n0 * 16 + lrow) * 2) ^ sw0)) = (u16)p0;
        *reinterpret_cast<u16*>(bb + (row0_ + 1) * 256 + (((n0 * 16 + lrow) * 2) ^ sw1)) = (u16)(p0 >> 16);
        *reinterpret_cast<u16*>(bb + row0_ * 256       + (((n1 * 16 + lrow) * 2) ^ sw0)) = (u16)p1;
        *reinterpret_cast<u16*>(bb + (row0_ + 1) * 256 + (((n1 * 16 + lrow) * 2) ^ sw1)) = (u16)(p1 >> 16);
      }
    }
    // ---- layer 1 phase B: m = 4..6 (reads rows 64..111, untouched by writes above)
    f4 cB0[3], cB1[3];
    #pragma unroll
    for(int m = 0; m < 3; m++){
      int arow = (m + 4) * 16 + lrow, sw = arow & 7;
      bf8 a[4];
      #pragma unroll
      for(int k = 0; k < 4; k++)
        a[k] = *reinterpret_cast<const bf8*>(bb + arow * 256 + (((k * 4 + lk) ^ sw) << 4));
      bf8 a4 = {0,0,0,0,0,0,0,0};
      if(lk == 0) a4 = *reinterpret_cast<const bf8*>(tb + arow * 16);
      f4 c0 = {0.f,0.f,0.f,0.f}, c1 = {0.f,0.f,0.f,0.f};
      #pragma unroll
      for(int k = 0; k < 4; k++){
        c0 = __builtin_amdgcn_mfma_f32_16x16x32_bf16(a[k], w1a[k], c0, 0, 0, 0);
        c1 = __builtin_amdgcn_mfma_f32_16x16x32_bf16(a[k], w1b[k], c1, 0, 0, 0);
      }
      c0 = __builtin_amdgcn_mfma_f32_16x16x32_bf16(a4, w1a[4], c0, 0, 0, 0);
      c1 = __builtin_amdgcn_mfma_f32_16x16x32_bf16(a4, w1b[4], c1, 0, 0, 0);
      cB0[m] = c0; cB1[m] = c1;
    }
    __syncthreads();   // BAR3: all warps done reading rows 64..111

    #pragma unroll
    for(int m = 0; m < 3; m++){
      #pragma unroll
      for(int qp = 0; qp < 2; qp++){
        float v0 = cB0[m][2*qp]   + b1a; v0 = v0 > 0.f ? v0 : 0.f;
        float u0 = cB0[m][2*qp+1] + b1a; u0 = u0 > 0.f ? u0 : 0.f;
        float v1 = cB1[m][2*qp]   + b1b; v1 = v1 > 0.f ? v1 : 0.f;
        float u1 = cB1[m][2*qp+1] + b1b; u1 = u1 > 0.f ? u1 : 0.f;
        u32 p0 = cvtpk(v0, u0), p1 = cvtpk(v1, u1);
        int row0_ = (m + 4) * 16 + lk * 4 + 2 * qp;
        int sw0 = (row0_ & 7) << 4, sw1 = ((row0_ + 1) & 7) << 4;
        *reinterpret_cast<u16*>(bb + row0_ * 256       + (((n0 * 16 + lrow) * 2) ^ sw0)) = (u16)p0;
        *reinterpret_cast<u16*>(bb + (row0_ + 1) * 256 + (((n0 * 16 + lrow) * 2) ^ sw1)) = (u16)(p0 >> 16);
        *reinterpret_cast<u16*>(bb + row0_ * 256       + (((n1 * 16 + lrow) * 2) ^ sw0)) = (u16)p1;
        *reinterpret_cast<u16*>(bb + (row0_ + 1) * 256 + (((n1 * 16 + lrow) * 2) ^ sw1)) = (u16)(p1 >> 16);
      }
    }
    __syncthreads();   // BAR4: h1 complete

    // ---- layer 2 + column-sum
    bf8 w2a[4], w2b[4];
    #pragma unroll
    for(int k = 0; k < 4; k++){ w2a[k] = *fragp(packed, 15, n0, k, lane); w2b[k] = *fragp(packed, 15, n1, k, lane); }
    float b2a = pm_b2[n0 * 16 + lrow], b2b = pm_b2[n1 * 16 + lrow];
    float acc0 = 0.f, acc1 = 0.f;
    #pragma unroll
    for(int m = 0; m < 7; m++){
      int arow = m * 16 + lrow, sw = arow & 7;
      bf8 a[4];
      #pragma unroll
      for(int k = 0; k < 4; k++)
        a[k] = *reinterpret_cast<const bf8*>(bb + arow * 256 + (((k * 4 + lk) ^ sw) << 4));
      f4 c0 = {0.f,0.f,0.f,0.f}, c1 = {0.f,0.f,0.f,0.f};
      #pragma unroll
      for(int k = 0; k < 4; k++){
        c0 = __builtin_amdgcn_mfma_f32_16x16x32_bf16(a[k], w2a[k], c0, 0, 0, 0);
        c1 = __builtin_amdgcn_mfma_f32_16x16x32_bf16(a[k], w2b[k], c1, 0, 0, 0);
      }
      #pragma unroll
      for(int q = 0; q < 4; q++){
        int rr = m * 16 + lk * 4 + q;
        if(rr < 99){
          float v0 = c0[q] + b2a; acc0 += (v0 > 0.f ? v0 : 0.f);
          float v1 = c1[q] + b2b; acc1 += (v1 > 0.f ? v1 : 0.f);
        }
      }
    }
    acc0 += __shfl_xor(acc0, 16); acc0 += __shfl_xor(acc0, 32);
    acc1 += __shfl_xor(acc1, 16); acc1 += __shfl_xor(acc1, 32);
    if(lane < 16){
      float* dst = pnode + ((size_t)b * 100 + r) * 128;
      dst[n0 * 16 + lane] = acc0 * (1.0f / 99.0f);
      dst[n1 * 16 + lane] = acc1 * (1.0f / 99.0f);
    }
  }
  __syncthreads();   // BAR5: all warps done reading pm h1 before msg overwrites bufA

  // ================= msg phase =================
  {
    bf8 w2a[4], w2b[4];
    #pragma unroll
    for(int k = 0; k < 4; k++){ w2a[k] = *fragp(packed, 13, n0, k, lane); w2b[k] = *fragp(packed, 13, n1, k, lane); }
    float b2a = msg_b2[n0 * 16 + lrow], b2b = msg_b2[n1 * 16 + lrow];
    int c4 = t & 31;
    float4 pt = *reinterpret_cast<const float4*>(Ptop + ((size_t)b * 100 + r) * 128 + c4 * 4);
    float4 mb = *reinterpret_cast<const float4*>(msg_b1 + c4 * 4);
    pt.x += mb.x; pt.y += mb.y; pt.z += mb.z; pt.w += mb.w;
    // h1 = tanh(pt + Pbot[s]) -> bufA (swizzled 8B writes)
    for(int row = t >> 5; row < 99; row += 8){
      int s = row + (row >= r ? 1 : 0);
      float4 v = *reinterpret_cast<const float4*>(Pbot + ((size_t)b * 100 + s) * 128 + c4 * 4);
      u32 pk[2] = {cvtpk(tanhF(pt.x + v.x), tanhF(pt.y + v.y)),
                   cvtpk(tanhF(pt.z + v.z), tanhF(pt.w + v.w))};
      *reinterpret_cast<uint2*>(bb + row * 256 + ((8 * c4) ^ ((row & 7) << 4))) = *reinterpret_cast<const uint2*>(pk);
    }
    __syncthreads();   // BAR6: msg h1 staged
    float acc0 = 0.f, acc1 = 0.f;
    #pragma unroll
    for(int m = 0; m < 7; m++){
      int arow = m * 16 + lrow, sw = arow & 7;
      bf8 a[4];
      #pragma unroll
      for(int k = 0; k < 4; k++)
        a[k] = *reinterpret_cast<const bf8*>(bb + arow * 256 + (((k * 4 + lk) ^ sw) << 4));
      f4 c0 = {0.f,0.f,0.f,0.f}, c1 = {0.f,0.f,0.f,0.f};
      #pragma unroll
      for(int k = 0; k < 4; k++){
        c0 = __builtin_amdgcn_mfma_f32_16x16x32_bf16(a[k], w2a[k], c0, 0, 0, 0);
        c1 = __builtin_amdgcn_mfma_f32_16x16x32_bf16(a[k], w2b[k], c1, 0, 0, 0);
      }
      #pragma unroll
      for(int q = 0; q < 4; q++){
        int rr = m * 16 + lk * 4 + q;
        if(rr < 99){
          acc0 += tanhF(c0[q] + b2a);
          acc1 += tanhF(c1[q] + b2b);
        }
      }
    }
    acc0 += __shfl_xor(acc0, 16); acc0 += __shfl_xor(acc0, 32);
    acc1 += __shfl_xor(acc1, 16); acc1 += __shfl_xor(acc1, 32);
    if(lane < 16){
      float* dst = hnode + ((size_t)b * 100 + r) * 128;
      dst[n0 * 16 + lane] = acc0 * (1.0f / 99.0f);
      dst[n1 * 16 + lane] = acc1 * (1.0f / 99.0f);
    }
  }
}

// ---------- K3: GRU gates + out MLP (64 rows/block, warp = nt, weights in regs) ----------
__global__ __launch_bounds__(512) void k_final(
    const float* __restrict__ hnode, const float* __restrict__ pnode,
    const float* __restrict__ res2, const float* __restrict__ hidden,
    const u16* __restrict__ packed,
    const float* __restrict__ ir_b, const float* __restrict__ ii_b, const float* __restrict__ in_b,
    const float* __restrict__ ob1, const float* __restrict__ ob2, const float* __restrict__ ob3,
    float* __restrict__ out_pred, float* __restrict__ out_hid)
{
  __shared__ __align__(16) u16 hn[64 * 136];
  __shared__ __align__(16) u16 pr[64 * 136];
  __shared__ __align__(16) u16 hw[64 * 136];
  int row0 = blockIdx.x * 64;
  int t = threadIdx.x, lane = t & 63, w = t >> 6;
  int lrow = lane & 15, lk = lane >> 4;
  for(int i = t; i < 64 * 128; i += 512){
    int rr = i >> 7, cc = i & 127;
    hn[rr * 136 + cc] = f2bf(hnode[(row0 + rr) * 128 + cc]);
    pr[rr * 136 + cc] = f2bf(pnode[(row0 + rr) * 128 + cc] + res2[(row0 + rr) * 128 + cc]);
  }
  int col = w * 16 + lrow;
  bf8 mhr[4], mhi[4], mhh[4], mir[4], mii[4], min_[4];
  #pragma unroll
  for(int k = 0; k < 4; k++){
    mhr[k]  = *fragp(packed, 2, w, k, lane);
    mhi[k]  = *fragp(packed, 3, w, k, lane);
    mhh[k]  = *fragp(packed, 4, w, k, lane);
    mir[k]  = *fragp(packed, 7, w, k, lane);
    mii[k]  = *fragp(packed, 8, w, k, lane);
    min_[k] = *fragp(packed, 9, w, k, lane);
  }
  float bir = ir_b[col], bii = ii_b[col], bin = in_b[col];
  __syncthreads();
  #pragma unroll
  for(int m = 0; m < 4; m++){
    bf8 a[4], p[4];
    #pragma unroll
    for(int k = 0; k < 4; k++){
      a[k] = *reinterpret_cast<const bf8*>(&hn[(m * 16 + lrow) * 136 + k * 32 + lk * 8]);
      p[k] = *reinterpret_cast<const bf8*>(&pr[(m * 16 + lrow) * 136 + k * 32 + lk * 8]);
    }
    f4 cR = {0.f,0.f,0.f,0.f}, cI = {0.f,0.f,0.f,0.f}, cN = {0.f,0.f,0.f,0.f};
    f4 dR = {0.f,0.f,0.f,0.f}, dI = {0.f,0.f,0.f,0.f}, dN = {0.f,0.f,0.f,0.f};
    #pragma unroll
    for(int k = 0; k < 4; k++){
      cR = __builtin_amdgcn_mfma_f32_16x16x32_bf16(a[k], mhr[k],  cR, 0, 0, 0);
      cI = __builtin_amdgcn_mfma_f32_16x16x32_bf16(a[k], mhi[k],  cI, 0, 0, 0);
      cN = __builtin_amdgcn_mfma_f32_16x16x32_bf16(a[k], mhh[k],  cN, 0, 0, 0);
      dR = __builtin_amdgcn_mfma_f32_16x16x32_bf16(p[k], mir[k],  dR, 0, 0, 0);
      dI = __builtin_amdgcn_mfma_f32_16x16x32_bf16(p[k], mii[k],  dI, 0, 0, 0);
      dN = __builtin_amdgcn_mfma_f32_16x16x32_bf16(p[k], min_[k], dN, 0, 0, 0);
    }
    #pragma unroll
    for(int q = 0; q < 4; q++){
      int gr = row0 + m * 16 + lk * 4 + q;
      float rv = sigF(dR[q] + bir + cR[q]);
      float iv = sigF(dI[q] + bii + cI[q]);
      float nv = tanhF(dN[q] + bin + rv * cN[q]);
      float hold = hidden[gr * 128 + col];
      float hnew = (1.f - iv) * nv + iv * hold;
      out_hid[gr * 128 + col] = hnew;
      hw[(m * 16 + lk * 4 + q) * 136 + col] = f2bf(hnew);
    }
  }
  __syncthreads();
  {
    bf8 m10[4];
    #pragma unroll
    for(int k = 0; k < 4; k++) m10[k] = *fragp(packed, 10, w, k, lane);
    float bb = ob1[col];
    #pragma unroll
    for(int m = 0; m < 4; m++){
      f4 c = {0.f,0.f,0.f,0.f};
      #pragma unroll
      for(int k = 0; k < 4; k++){
        bf8 a = *reinterpret_cast<const bf8*>(&hw[(m * 16 + lrow) * 136 + k * 32 + lk * 8]);
        c = __builtin_amdgcn_mfma_f32_16x16x32_bf16(a, m10[k], c, 0, 0, 0);
      }
      #pragma unroll
      for(int q = 0; q < 4; q++){
        float v = c[q] + bb; v = v > 0.f ? v : 0.f;
        hn[(m * 16 + lk * 4 + q) * 136 + col] = f2bf(v);
      }
    }
  }
  __syncthreads();
  {
    bf8 m11[4];
    #pragma unroll
    for(int k = 0; k < 4; k++) m11[k] = *fragp(packed, 11, w, k, lane);
    float bb = ob2[col];
    #pragma unroll
    for(int m = 0; m < 4; m++){
      f4 c = {0.f,0.f,0.f,0.f};
      #pragma unroll
      for(int k = 0; k < 4; k++){
        bf8 a = *reinterpret_cast<const bf8*>(&hn[(m * 16 + lrow) * 136 + k * 32 + lk * 8]);
        c = __builtin_amdgcn_mfma_f32_16x16x32_bf16(a, m11[k], c, 0, 0, 0);
      }
      #pragma unroll
      for(int q = 0; q < 4; q++){
        float v = c[q] + bb; v = v > 0.f ? v : 0.f;
        pr[(m * 16 + lk * 4 + q) * 136 + col] = f2bf(v);
      }
    }
  }
  __syncthreads();
  {
    bf8 m12[4];
    #pragma unroll
    for(int k = 0; k < 4; k++) m12[k] = *fragp(packed, 12, w, k, lane);
    float bb = ob3[col];
    #pragma unroll
    for(int m = 0; m < 4; m++){
      f4 c = {0.f,0.f,0.f,0.f};
      #pragma unroll
      for(int k = 0; k < 4; k++){
        bf8 a = *reinterpret_cast<const bf8*>(&pr[(m * 16 + lrow) * 136 + k * 32 + lk * 8]);
        c = __builtin_amdgcn_mfma_f32_16x16x32_bf16(a, m12[k], c, 0, 0, 0);
      }
      #pragma unroll
      for(int q = 0; q < 4; q++)
        out_pred[(row0 + m * 16 + lk * 4 + q) * 128 + col] = c[q] + bb;
    }
  }
}

// ---------- host ----------
extern "C" void kernel_launch(void* const* d_in, const int* in_sizes, int n_in,
                              void* d_out, int out_size, void* d_ws, size_t ws_size,
                              hipStream_t stream)
{
  const float* inputs = (const float*)d_in[0];
  const float* edge   = (const float*)d_in[1];
  const float* hidden = (const float*)d_in[2];
  const float* msg_w1 = (const float*)d_in[3];
  const float* msg_b1 = (const float*)d_in[4];
  const float* msg_w2 = (const float*)d_in[5];
  const float* msg_b2 = (const float*)d_in[6];
  const float* pm_w1  = (const float*)d_in[7];
  const float* pm_b1  = (const float*)d_in[8];
  const float* pm_w2  = (const float*)d_in[9];
  const float* pm_b2  = (const float*)d_in[10];
  const float* res_w1 = (const float*)d_in[11];
  const float* res_b1 = (const float*)d_in[12];
  const float* res_w2 = (const float*)d_in[13];
  const float* res_b2 = (const float*)d_in[14];
  const float* ir_w = (const float*)d_in[15]; const float* ir_b = (const float*)d_in[16];
  const float* ii_w = (const float*)d_in[17]; const float* ii_b = (const float*)d_in[18];
  const float* in_w = (const float*)d_in[19]; const float* in_b = (const float*)d_in[20];
  const float* hr_w = (const float*)d_in[21];
  const float* hi_w = (const float*)d_in[22];
  const float* hh_w = (const float*)d_in[23];
  const float* out_w1 = (const float*)d_in[24]; const float* out_b1 = (const float*)d_in[25];
  const float* out_w2 = (const float*)d_in[26]; const float* out_b2 = (const float*)d_in[27];
  const float* out_w3 = (const float*)d_in[28]; const float* out_b3 = (const float*)d_in[29];

  char* ws = (char*)d_ws;
  u16*   packed = (u16*)ws;                                     // 565248 B used (1 MB reserved)
  float* Ptop   = (float*)(ws + (1 << 20));                     // 1638400 B each
  float* Pbot   = (float*)(ws + (1 << 20) + 1 * 1638400);
  float* res2   = (float*)(ws + (1 << 20) + 2 * 1638400);
  float* hnode  = (float*)(ws + (1 << 20) + 3 * 1638400);
  float* pnode  = (float*)(ws + (1 << 20) + 4 * 1638400);

  WPtrs wp;
  wp.p[0]  = msg_w1;             // msg_w1 top (recv half)
  wp.p[1]  = msg_w1 + 128 * 128; // msg_w1 bottom (send half)
  wp.p[2]  = hr_w;  wp.p[3]  = hi_w;  wp.p[4]  = hh_w;
  wp.p[5]  = res_w1; wp.p[6] = res_w2;
  wp.p[7]  = ir_w;  wp.p[8]  = ii_w;  wp.p[9]  = in_w;
  wp.p[10] = out_w1; wp.p[11] = out_w2; wp.p[12] = out_w3;
  wp.p[13] = msg_w2; wp.p[14] = pm_w1; wp.p[15] = pm_w2;

  k_pack<<<17, 256, 0, stream>>>(wp, packed);
  k_node_pre<<<50, 512, 0, stream>>>(hidden, inputs, packed, res_b1, res_b2, Ptop, Pbot, res2);
  k_edge<<<3200, 256, 0, stream>>>(edge, Ptop, Pbot, msg_b1, msg_b2, pm_b1, pm_b2,
                                   packed, hnode, pnode);
  float* outp = (float*)d_out;
  k_final<<<50, 512, 0, stream>>>(hnode, pnode, res2, hidden, packed,
                                  ir_b, ii_b, in_b, out_b1, out_b2, out_b3,
                                  outp, outp + 32 * 100 * 128);
}